// Round 5
// baseline (257.373 us; speedup 1.0000x reference)
//
#include <hip/hip_runtime.h>
#include <hip/hip_bf16.h>
#include <math.h>

#define D 64
#define SCAN_B 256

typedef __hip_bfloat16 bf16;

// ---------- K1: fused dst-histogram (rank capture) + xt = x @ W (bf16 out) ----
// W lives in LDS (transposed, padded) instead of 64 VGPRs/lane: VGPR ~50 ->
// 8 waves/SIMD, so the atomic-return and load latencies actually hide.
__global__ __launch_bounds__(256, 8) void gemm_count_kernel(
    const float* __restrict__ x, const float* __restrict__ W,
    const int* __restrict__ ei,
    bf16* __restrict__ xt, int* __restrict__ counts, int* __restrict__ rank,
    int n_nodes, int n_edges)
{
    __shared__ float Wt[64 * 68];   // Wt[d][k] at d*68+k; 272 B row pitch

    // stage W transposed into LDS (one-time, 4096 elems)
    for (int idx = threadIdx.x; idx < 4096; idx += 256) {
        int k = idx >> 6, dd = idx & 63;
        Wt[dd * 68 + k] = W[idx];
    }

    const int gid = blockIdx.x * blockDim.x + threadIdx.x;
    const int nth = gridDim.x * blockDim.x;

    // phase A: histogram of dst, capturing per-edge rank (fire atomics while
    // LDS staging settles; latency hides under TLP)
    for (int e = gid; e < n_edges; e += nth) {
        int dst = ei[n_edges + e];
        rank[e] = atomicAdd(&counts[dst], 1);
    }

    __syncthreads();

    // phase B: one wave per row, lane d owns output column d
    const int d = threadIdx.x & 63;
    const int wid = gid >> 6;
    const int waves_total = nth >> 6;
    const float4* wrow = reinterpret_cast<const float4*>(&Wt[d * 68]);

    for (int row = wid; row < n_nodes; row += waves_total) {
        const float4* xr = reinterpret_cast<const float4*>(x + (size_t)row * 64);
        float acc = 0.f;
#pragma unroll 4
        for (int kk = 0; kk < 16; ++kk) {
            float4 xv = xr[kk];
            float4 wv = wrow[kk];
            acc = fmaf(xv.x, wv.x, acc);
            acc = fmaf(xv.y, wv.y, acc);
            acc = fmaf(xv.z, wv.z, acc);
            acc = fmaf(xv.w, wv.w, acc);
        }
        xt[(size_t)row * 64 + d] = __float2bfloat16(acc);
    }
}

// ---------- K2: block scan (exclusive) + block totals ----------
__global__ __launch_bounds__(SCAN_B) void scan1_kernel(const int* __restrict__ c,
                                                       int* __restrict__ excl,
                                                       int* __restrict__ partials,
                                                       int n) {
    __shared__ int s[SCAN_B];
    int i = blockIdx.x * SCAN_B + threadIdx.x;
    int v = (i < n) ? c[i] : 0;
    s[threadIdx.x] = v;
    __syncthreads();
    for (int off = 1; off < SCAN_B; off <<= 1) {
        int t = (threadIdx.x >= off) ? s[threadIdx.x - off] : 0;
        __syncthreads();
        s[threadIdx.x] += t;
        __syncthreads();
    }
    if (i < n) excl[i] = s[threadIdx.x] - v;
    if (threadIdx.x == SCAN_B - 1) partials[blockIdx.x] = s[SCAN_B - 1];
}

// ---------- K3: apply partials prefix (each block reduces its own prefix) ----
__global__ __launch_bounds__(SCAN_B) void scan23_kernel(int* __restrict__ offsets,
                                                        const int* __restrict__ partials,
                                                        int n, int n_edges) {
    __shared__ int red[SCAN_B];
    int psum = 0;
    for (int i = threadIdx.x; i < blockIdx.x; i += SCAN_B) psum += partials[i];
    red[threadIdx.x] = psum;
    __syncthreads();
    for (int off = SCAN_B / 2; off > 0; off >>= 1) {
        if (threadIdx.x < off) red[threadIdx.x] += red[threadIdx.x + off];
        __syncthreads();
    }
    int base = red[0];
    int i = blockIdx.x * SCAN_B + threadIdx.x;
    if (i < n) offsets[i] += base;
    if (blockIdx.x == 0 && threadIdx.x == 0) offsets[n] = n_edges;
}

// ---------- K4: CSR fill — NO atomics, pure dataflow scatter ----------
__global__ __launch_bounds__(256) void fill_kernel(const int* __restrict__ ei,
                                                   const float* __restrict__ ea,
                                                   const int* __restrict__ offs,
                                                   const int* __restrict__ rank,
                                                   int2* __restrict__ csr,
                                                   int n_edges) {
    int e = blockIdx.x * blockDim.x + threadIdx.x;
    if (e >= n_edges) return;
    int dst = ei[n_edges + e];
    int pos = offs[dst] + rank[e];
    long long v = ((long long)__float_as_int(ea[e]) << 32) | (unsigned)ei[e];
    __builtin_nontemporal_store(v, (long long*)(csr + pos));
}

// ---------- K5: gather, one wave per node, lane = dim, 4-wide edge ILP ------
__global__ __launch_bounds__(256) void gather_kernel(const int* __restrict__ offsets,
                                                     const int2* __restrict__ csr,
                                                     const bf16* __restrict__ xt,
                                                     const float* __restrict__ ewW,
                                                     const float* __restrict__ ewb,
                                                     const float* __restrict__ bias,
                                                     float* __restrict__ out,
                                                     int n_nodes) {
    const int d = threadIdx.x & 63;
    const int node = (blockIdx.x * blockDim.x + threadIdx.x) >> 6;
    if (node >= n_nodes) return;

    const float wd = ewW[d];
    const float bd = ewb[d];
    const int start = offsets[node];
    const int end = offsets[node + 1];

    float acc = 0.f;
    int k = start;
    for (; k + 4 <= end; k += 4) {
        long long q0 = __builtin_nontemporal_load((const long long*)(csr + k + 0));
        long long q1 = __builtin_nontemporal_load((const long long*)(csr + k + 1));
        long long q2 = __builtin_nontemporal_load((const long long*)(csr + k + 2));
        long long q3 = __builtin_nontemporal_load((const long long*)(csr + k + 3));
        int s0 = (int)(unsigned)q0, s1 = (int)(unsigned)q1;
        int s2 = (int)(unsigned)q2, s3 = (int)(unsigned)q3;
        float x0 = __bfloat162float(xt[(size_t)s0 * 64 + d]);
        float x1 = __bfloat162float(xt[(size_t)s1 * 64 + d]);
        float x2 = __bfloat162float(xt[(size_t)s2 * 64 + d]);
        float x3 = __bfloat162float(xt[(size_t)s3 * 64 + d]);
        float a0 = __int_as_float((int)(q0 >> 32));
        float a1 = __int_as_float((int)(q1 >> 32));
        float a2 = __int_as_float((int)(q2 >> 32));
        float a3 = __int_as_float((int)(q3 >> 32));
        float w0 = 1.f / (1.f + __expf(-(a0 * wd + bd)));
        float w1 = 1.f / (1.f + __expf(-(a1 * wd + bd)));
        float w2 = 1.f / (1.f + __expf(-(a2 * wd + bd)));
        float w3 = 1.f / (1.f + __expf(-(a3 * wd + bd)));
        acc = fmaf(x0, w0, acc);
        acc = fmaf(x1, w1, acc);
        acc = fmaf(x2, w2, acc);
        acc = fmaf(x3, w3, acc);
    }
    for (; k < end; ++k) {
        long long q = __builtin_nontemporal_load((const long long*)(csr + k));
        int s = (int)(unsigned)q;
        float xv = __bfloat162float(xt[(size_t)s * 64 + d]);
        float a = __int_as_float((int)(q >> 32));
        float w = 1.f / (1.f + __expf(-(a * wd + bd)));
        acc = fmaf(xv, w, acc);
    }
    float r = acc + bias[d];
    __builtin_nontemporal_store(r, out + (size_t)node * 64 + d);
}

// ---------- fallback (atomic scatter) ----------
__global__ __launch_bounds__(256) void init_out_kernel(float* __restrict__ out,
                                                       const float* __restrict__ bias,
                                                       int n_f4) {
    int i = blockIdx.x * blockDim.x + threadIdx.x;
    if (i >= n_f4) return;
    float4 b4 = reinterpret_cast<const float4*>(bias)[i & 15];
    reinterpret_cast<float4*>(out)[i] = b4;
}

__global__ __launch_bounds__(256) void edge_atomic_kernel(const int* __restrict__ ei,
                                                          const float* __restrict__ ea,
                                                          const bf16* __restrict__ xt,
                                                          const float* __restrict__ ewW,
                                                          const float* __restrict__ ewb,
                                                          float* __restrict__ out,
                                                          int n_edges) {
    const int gid = blockIdx.x * blockDim.x + threadIdx.x;
    const int d0 = (gid & 15) * 4;
    int e = gid >> 4;
    const int estride = (gridDim.x * blockDim.x) >> 4;
    for (; e < n_edges; e += estride) {
        const int src = ei[e];
        const int dst = ei[n_edges + e];
        const float a = ea[e];
        float xv0 = __bfloat162float(xt[(size_t)src * 64 + d0 + 0]);
        float xv1 = __bfloat162float(xt[(size_t)src * 64 + d0 + 1]);
        float xv2 = __bfloat162float(xt[(size_t)src * 64 + d0 + 2]);
        float xv3 = __bfloat162float(xt[(size_t)src * 64 + d0 + 3]);
        float w0 = 1.f / (1.f + __expf(-(a * ewW[d0 + 0] + ewb[d0 + 0])));
        float w1 = 1.f / (1.f + __expf(-(a * ewW[d0 + 1] + ewb[d0 + 1])));
        float w2 = 1.f / (1.f + __expf(-(a * ewW[d0 + 2] + ewb[d0 + 2])));
        float w3 = 1.f / (1.f + __expf(-(a * ewW[d0 + 3] + ewb[d0 + 3])));
        float* op = out + (size_t)dst * 64 + d0;
        unsafeAtomicAdd(op + 0, xv0 * w0);
        unsafeAtomicAdd(op + 1, xv1 * w1);
        unsafeAtomicAdd(op + 2, xv2 * w2);
        unsafeAtomicAdd(op + 3, xv3 * w3);
    }
}

extern "C" void kernel_launch(void* const* d_in, const int* in_sizes, int n_in,
                              void* d_out, int out_size, void* d_ws, size_t ws_size,
                              hipStream_t stream) {
    const float* x      = (const float*)d_in[0];
    const int*   ei     = (const int*)d_in[1];
    const float* ea     = (const float*)d_in[2];
    const float* weight = (const float*)d_in[3];
    const float* ewW    = (const float*)d_in[4];
    const float* ewb    = (const float*)d_in[5];
    const float* bias   = (const float*)d_in[6];
    float* out = (float*)d_out;

    const int n_nodes = in_sizes[0] / D;   // 100000
    const int n_edges = in_sizes[2];       // 1600000

    // workspace layout
    char* ws = (char*)d_ws;
    const size_t xt_bytes   = (size_t)n_nodes * D * sizeof(bf16);      // 12.8 MB
    const size_t off_off    = (xt_bytes + 7) & ~(size_t)7;
    const size_t off_bytes  = ((size_t)n_nodes + 4) * sizeof(int);
    const size_t part_off   = off_off + off_bytes;
    const size_t part_bytes = 512 * sizeof(int);
    const size_t rank_off   = part_off + part_bytes;
    const size_t rank_bytes = (size_t)n_edges * sizeof(int);           // 6.4 MB
    size_t csr_off          = (rank_off + rank_bytes + 7) & ~(size_t)7;
    const size_t csr_bytes  = (size_t)n_edges * sizeof(int2);          // 12.8 MB
    const size_t need       = csr_off + csr_bytes;                     // ~32.5 MB

    bf16* xt   = (bf16*)(ws);
    int*  offs = (int*)(ws + off_off);
    int*  parts= (int*)(ws + part_off);
    int*  rank = (int*)(ws + rank_off);
    int2* csr  = (int2*)(ws + csr_off);

    const bool have_ws = (ws_size >= need);

    if (have_ws) {
        hipMemsetAsync(offs, 0, off_bytes, stream);
        gemm_count_kernel<<<2048, 256, 0, stream>>>(x, weight, ei, xt, offs, rank,
                                                    n_nodes, n_edges);

        const int nscan_blocks = (n_nodes + SCAN_B - 1) / SCAN_B;   // 391
        scan1_kernel<<<nscan_blocks, SCAN_B, 0, stream>>>(offs, offs, parts, n_nodes);
        scan23_kernel<<<nscan_blocks, SCAN_B, 0, stream>>>(offs, parts, n_nodes, n_edges);
        fill_kernel<<<(n_edges + 255) / 256, 256, 0, stream>>>(ei, ea, offs, rank, csr, n_edges);
        gather_kernel<<<(n_nodes * 64 + 255) / 256, 256, 0, stream>>>(offs, csr, xt, ewW, ewb,
                                                                      bias, out, n_nodes);
    } else {
        // fallback: atomic scatter path (needs only xt)
        gemm_count_kernel<<<2048, 256, 0, stream>>>(x, weight, ei, xt,
                                                    /*counts=*/nullptr, /*rank=*/nullptr,
                                                    n_nodes, 0 /* skip histogram */);
        int n_f4 = n_nodes * (D / 4);
        init_out_kernel<<<(n_f4 + 255) / 256, 256, 0, stream>>>(out, bias, n_f4);
        edge_atomic_kernel<<<4096, 256, 0, stream>>>(ei, ea, xt, ewW, ewb, out, n_edges);
    }
}